// Round 4
// baseline (1302.681 us; speedup 1.0000x reference)
//
#include <hip/hip_runtime.h>

#define N_NODES 100000
#define N_EDGES 1000000
#define HID 64

// x[n] = node_emb[z[n]]  (16 threads per node, float4 each)
__global__ __launch_bounds__(256) void gather_kernel(
    const float* __restrict__ node_emb, const int* __restrict__ z,
    float* __restrict__ x)
{
    int t = blockIdx.x * 256 + threadIdx.x;
    int n = t >> 4, c = t & 15;
    if (n >= N_NODES) return;
    int zi = z[n];
    float4 v = ((const float4*)(node_emb + (size_t)zi * HID))[c];
    ((float4*)(x + (size_t)n * HID))[c] = v;
}

// W2T[conv][c][j] = W2[conv][j][c]  (3 x 64 x 64)
__global__ __launch_bounds__(256) void trans_kernel(
    const float* __restrict__ W2, float* __restrict__ W2T)
{
    for (int idx = blockIdx.x * 256 + threadIdx.x; idx < 3 * HID * HID;
         idx += gridDim.x * 256) {
        int conv = idx >> 12, rem = idx & 4095, j = rem >> 6, c = rem & 63;
        W2T[(conv << 12) + (c << 6) + j] = W2[idx];
    }
}

// offs[dst[e]] += 1  (degree histogram; offs pre-zeroed)
__global__ __launch_bounds__(256) void hist_kernel(
    const int* __restrict__ dst, int* __restrict__ offs)
{
    int e = blockIdx.x * 256 + threadIdx.x;
    if (e < N_EDGES) atomicAdd(&offs[dst[e]], 1);
}

// Device-wide scan, pass 1: per-block (1024-elem chunk) exclusive scan,
// block total to bsum[block].
__global__ __launch_bounds__(1024) void scan1_kernel(
    int* __restrict__ offs, int* __restrict__ bsum)
{
    __shared__ int wsum[16];
    int tid = threadIdx.x, lane = tid & 63, wid = tid >> 6;
    int i = blockIdx.x * 1024 + tid;
    int v = (i < N_NODES) ? offs[i] : 0;
    int s = v;
#pragma unroll
    for (int d = 1; d < 64; d <<= 1) {
        int t = __shfl_up(s, (unsigned)d, 64);
        if (lane >= d) s += t;
    }
    if (lane == 63) wsum[wid] = s;
    __syncthreads();
    if (wid == 0) {
        int w = (lane < 16) ? wsum[lane] : 0;
#pragma unroll
        for (int d = 1; d < 16; d <<= 1) {
            int t = __shfl_up(w, (unsigned)d, 64);
            if (lane >= d) w += t;
        }
        if (lane < 16) wsum[lane] = w;
    }
    __syncthreads();
    int woff = (wid == 0) ? 0 : wsum[wid - 1];
    if (i < N_NODES) offs[i] = woff + s - v;     // exclusive within block
    if (tid == 0) bsum[blockIdx.x] = wsum[15];
}

// pass 2: exclusive scan of the <=128 block totals, in place. One block.
__global__ __launch_bounds__(128) void scan2_kernel(int* __restrict__ bsum, int nb)
{
    __shared__ int wsum2[2];
    int tid = threadIdx.x, lane = tid & 63, wid = tid >> 6;
    int v = (tid < nb) ? bsum[tid] : 0;
    int s = v;
#pragma unroll
    for (int d = 1; d < 64; d <<= 1) {
        int t = __shfl_up(s, (unsigned)d, 64);
        if (lane >= d) s += t;
    }
    if (lane == 63) wsum2[wid] = s;
    __syncthreads();
    int add = (wid == 1) ? wsum2[0] : 0;
    if (tid < nb) bsum[tid] = add + s - v;       // exclusive
}

// pass 3: add block offset; publish with atomicExch so fill's atomicAdd
// cursor RMW (other XCD) never sees a stale value.
__global__ __launch_bounds__(256) void scan3_kernel(
    int* __restrict__ offs, const int* __restrict__ bsum)
{
    int i = blockIdx.x * 256 + threadIdx.x;
    if (i < N_NODES) atomicExch(&offs[i], offs[i] + bsum[i >> 10]);
}

// eid2[slot] = (e, src[e]); offs becomes END offsets after this
// (start[n] = offs[n-1] afterwards, start[0] = 0).
__global__ __launch_bounds__(256) void fill_kernel(
    const int* __restrict__ src, const int* __restrict__ dst,
    int* __restrict__ offs, int2* __restrict__ eid2)
{
    int e = blockIdx.x * 256 + threadIdx.x;
    if (e < N_EDGES) {
        int d = dst[e];
        int pos = atomicAdd(&offs[d], 1);
        eid2[pos] = make_int2(e, src[e]);
    }
}

// Canonicalize each node's slot range to ascending edge-id order so the
// aggregation sum order is launch-invariant. Wave per node, 64-lane bitonic
// sort, INT_MAX padding. Degrees ~Poisson(10); P(deg>64) ~ 1e-40.
__global__ __launch_bounds__(256) void sort_kernel(
    const int* __restrict__ offs, int2* __restrict__ eid2)
{
    int gt = blockIdx.x * 256 + threadIdx.x;
    int n = gt >> 6;
    int lane = threadIdx.x & 63;
    if (n >= N_NODES) return;                 // wave-uniform
    int start = (n == 0) ? 0 : offs[n - 1];
    int end = offs[n];
    int deg = end - start;
    if (deg <= 1 || deg > 64) return;         // wave-uniform
    int ke = 0x7fffffff, vs = 0;
    if (lane < deg) { int2 t = eid2[start + lane]; ke = t.x; vs = t.y; }
#pragma unroll
    for (int k = 2; k <= 64; k <<= 1) {
        for (int j = k >> 1; j > 0; j >>= 1) {
            int partner = lane ^ j;
            int ke2 = __shfl(ke, partner, 64);
            int vs2 = __shfl(vs, partner, 64);
            bool up = ((lane & k) == 0);
            bool takemin = ((lane < partner) == up);
            bool sw = takemin ? (ke2 < ke) : (ke2 > ke);
            if (sw) { ke = ke2; vs = vs2; }
        }
    }
    if (lane < deg) eid2[start + lane] = make_int2(ke, vs);
}

// Wave-per-node aggregation, 4 edges per iteration.
// lane = (edge-slot j = lane>>4) x (channel-quad q = lane&15).
// Each lane loads float4 of x[src] and ea[e]; shfl_xor reduce over j.
__global__ __launch_bounds__(256) void agg_kernel(
    const float* __restrict__ x, const float* __restrict__ ea,
    const int2* __restrict__ eid2, const int* __restrict__ offs,
    float* __restrict__ agg)
{
    int gt = blockIdx.x * 256 + threadIdx.x;
    int n = gt >> 6;                         // wave-uniform
    int lane = threadIdx.x & 63;
    int j = lane >> 4, q = lane & 15;
    if (n >= N_NODES) return;
    int start = (n == 0) ? 0 : offs[n - 1];
    int end = offs[n];
    float4 acc = make_float4(0.f, 0.f, 0.f, 0.f);
    for (int i = start; i < end; i += 4) {   // uniform trip count
        int idx = i + j;
        if (idx < end) {
            int2 p = eid2[idx];
            float4 a = ((const float4*)(ea + (size_t)p.x * HID))[q];
            float4 v = ((const float4*)(x + (size_t)p.y * HID))[q];
            acc.x += fmaxf(v.x + a.x, 0.f);
            acc.y += fmaxf(v.y + a.y, 0.f);
            acc.z += fmaxf(v.z + a.z, 0.f);
            acc.w += fmaxf(v.w + a.w, 0.f);
        }
    }
    // reduce over the 4 edge-slots: lanes {q, q+16, q+32, q+48}
    acc.x += __shfl_xor(acc.x, 32, 64);
    acc.y += __shfl_xor(acc.y, 32, 64);
    acc.z += __shfl_xor(acc.z, 32, 64);
    acc.w += __shfl_xor(acc.w, 32, 64);
    acc.x += __shfl_xor(acc.x, 16, 64);
    acc.y += __shfl_xor(acc.y, 16, 64);
    acc.z += __shfl_xor(acc.z, 16, 64);
    acc.w += __shfl_xor(acc.w, 16, 64);
    if (lane < 16)
        ((float4*)(agg + (size_t)n * HID))[q] = acc;
}

// Per-node MLP, outer-product form. Weights read with WAVE-UNIFORM addresses
// from global -> compiler selects scalar (SMEM) loads; weight operands live
// in SGPRs, zero LDS traffic. W2T is the pre-transposed W2.
// o = (relu?)(W2 @ relu(W1 @ (agg+x) + b1) + b2) + x, in place on x.
__global__ __launch_bounds__(256) void mlp_kernel(
    const float* __restrict__ agg,
    const float* __restrict__ W1, const float* __restrict__ b1,
    const float* __restrict__ W2T, const float* __restrict__ b2,
    float* __restrict__ x, int last_relu)
{
    int n = blockIdx.x * 256 + threadIdx.x;
    if (n >= N_NODES) return;

    const float4* ap = (const float4*)(agg + (size_t)n * HID);
    const float4* xp = (const float4*)(x + (size_t)n * HID);

    float in[HID];
#pragma unroll
    for (int c = 0; c < 16; ++c) {
        float4 a = ap[c], b = xp[c];
        in[4*c+0] = a.x + b.x;
        in[4*c+1] = a.y + b.y;
        in[4*c+2] = a.z + b.z;
        in[4*c+3] = a.w + b.w;
    }

    float o[HID];
#pragma unroll
    for (int c = 0; c < HID; ++c) o[c] = b2[c];   // uniform -> scalar loads

    for (int j = 0; j < HID; ++j) {
        const float4* w1p = (const float4*)(W1 + (j << 6));   // uniform addr
        float a0 = 0.f, a1 = 0.f, a2 = 0.f, a3 = 0.f;
#pragma unroll
        for (int c = 0; c < 16; c += 4) {
            float4 wa = w1p[c+0], wb = w1p[c+1], wc = w1p[c+2], wd = w1p[c+3];
            a0 += in[4*c+ 0]*wa.x + in[4*c+ 1]*wa.y + in[4*c+ 2]*wa.z + in[4*c+ 3]*wa.w;
            a1 += in[4*c+ 4]*wb.x + in[4*c+ 5]*wb.y + in[4*c+ 6]*wb.z + in[4*c+ 7]*wb.w;
            a2 += in[4*c+ 8]*wc.x + in[4*c+ 9]*wc.y + in[4*c+10]*wc.z + in[4*c+11]*wc.w;
            a3 += in[4*c+12]*wd.x + in[4*c+13]*wd.y + in[4*c+14]*wd.z + in[4*c+15]*wd.w;
        }
        float h = fmaxf((a0 + a1) + (a2 + a3) + b1[j], 0.f);
        const float4* w2p = (const float4*)(W2T + (j << 6));  // uniform addr
#pragma unroll
        for (int c = 0; c < 16; ++c) {
            float4 w = w2p[c];
            o[4*c+0] += h * w.x;
            o[4*c+1] += h * w.y;
            o[4*c+2] += h * w.z;
            o[4*c+3] += h * w.w;
        }
    }

    float* orow = x + (size_t)n * HID;   // in-place: row-private
#pragma unroll
    for (int c = 0; c < 16; ++c) {
        float4 xv = xp[c];
        float4 r;
        r.x = (last_relu ? fmaxf(o[4*c+0], 0.f) : o[4*c+0]) + xv.x;
        r.y = (last_relu ? fmaxf(o[4*c+1], 0.f) : o[4*c+1]) + xv.y;
        r.z = (last_relu ? fmaxf(o[4*c+2], 0.f) : o[4*c+2]) + xv.z;
        r.w = (last_relu ? fmaxf(o[4*c+3], 0.f) : o[4*c+3]) + xv.w;
        ((float4*)orow)[c] = r;
    }
}

extern "C" void kernel_launch(void* const* d_in, const int* in_sizes, int n_in,
                              void* d_out, int out_size, void* d_ws, size_t ws_size,
                              hipStream_t stream) {
    const float* node_emb = (const float*)d_in[0];
    const float* W1 = (const float*)d_in[1];
    const float* b1 = (const float*)d_in[2];
    const float* W2 = (const float*)d_in[3];
    const float* b2 = (const float*)d_in[4];
    const float* ea = (const float*)d_in[5];
    const int* z = (const int*)d_in[6];
    const int* ei = (const int*)d_in[7];
    const int* src = ei;            // edge_index[0] = message sender
    const int* dst = ei + N_EDGES;  // edge_index[1] = aggregation target

    float* x = (float*)d_out;                       // node features live here

    char* w = (char*)d_ws;
    float* agg = (float*)w;                    w += (size_t)N_NODES * HID * 4;  // 25.6 MB
    int2* eid2 = (int2*)w;                     w += (size_t)N_EDGES * 8;        // 8 MB
    int* offs = (int*)w;                       w += (size_t)N_NODES * 4;        // 0.4 MB
    int* bsum = (int*)w;                       w += 128 * 4;
    float* w2t = (float*)w;                    w += 3 * HID * HID * 4;          // 48 KB

    const int eb = (N_EDGES + 255) / 256;            // 3907
    const int gather_blocks = (N_NODES * 16) / 256;  // 6250
    const int nodewave_blocks = (N_NODES * 64) / 256; // 25000
    const int mlp_blocks = (N_NODES + 255) / 256;    // 391
    const int nscan = (N_NODES + 1023) / 1024;       // 98

    // ---- CSR build + weight transpose (once, reused by all 3 convs) ----
    hipMemsetAsync(offs, 0, N_NODES * sizeof(int), stream);
    gather_kernel<<<gather_blocks, 256, 0, stream>>>(node_emb, z, x);
    trans_kernel<<<48, 256, 0, stream>>>(W2, w2t);
    hist_kernel<<<eb, 256, 0, stream>>>(dst, offs);
    scan1_kernel<<<nscan, 1024, 0, stream>>>(offs, bsum);
    scan2_kernel<<<1, 128, 0, stream>>>(bsum, nscan);
    scan3_kernel<<<mlp_blocks, 256, 0, stream>>>(offs, bsum);
    fill_kernel<<<eb, 256, 0, stream>>>(src, dst, offs, eid2);
    sort_kernel<<<nodewave_blocks, 256, 0, stream>>>(offs, eid2);

    // ---- 3 convs, x updated in place in d_out ----
    for (int conv = 0; conv < 3; ++conv) {
        agg_kernel<<<nodewave_blocks, 256, 0, stream>>>(x, ea, eid2, offs, agg);
        mlp_kernel<<<mlp_blocks, 256, 0, stream>>>(
            agg, W1 + conv * HID * HID, b1 + conv * HID,
            w2t + conv * HID * HID, b2 + conv * HID,
            x, conv < 2 ? 1 : 0);
    }
}

// Round 5
// 1244.187 us; speedup vs baseline: 1.0470x; 1.0470x over previous
//
#include <hip/hip_runtime.h>

#define N_NODES 100000
#define N_EDGES 1000000
#define HID 64

// x[n] = node_emb[z[n]]  (16 threads per node, float4 each)
__global__ __launch_bounds__(256) void gather_kernel(
    const float* __restrict__ node_emb, const int* __restrict__ z,
    float* __restrict__ x)
{
    int t = blockIdx.x * 256 + threadIdx.x;
    int n = t >> 4, c = t & 15;
    if (n >= N_NODES) return;
    int zi = z[n];
    float4 v = ((const float4*)(node_emb + (size_t)zi * HID))[c];
    ((float4*)(x + (size_t)n * HID))[c] = v;
}

// W2T[conv][c][j] = W2[conv][j][c]  (3 x 64 x 64)
__global__ __launch_bounds__(256) void trans_kernel(
    const float* __restrict__ W2, float* __restrict__ W2T)
{
    for (int idx = blockIdx.x * 256 + threadIdx.x; idx < 3 * HID * HID;
         idx += gridDim.x * 256) {
        int conv = idx >> 12, rem = idx & 4095, j = rem >> 6, c = rem & 63;
        W2T[(conv << 12) + (c << 6) + j] = W2[idx];
    }
}

// offs[dst[e]] += 1  (degree histogram; offs pre-zeroed)
__global__ __launch_bounds__(256) void hist_kernel(
    const int* __restrict__ dst, int* __restrict__ offs)
{
    int e = blockIdx.x * 256 + threadIdx.x;
    if (e < N_EDGES) atomicAdd(&offs[dst[e]], 1);
}

// Device-wide scan, pass 1: per-block (1024-elem chunk) exclusive scan,
// block total to bsum[block].
__global__ __launch_bounds__(1024) void scan1_kernel(
    int* __restrict__ offs, int* __restrict__ bsum)
{
    __shared__ int wsum[16];
    int tid = threadIdx.x, lane = tid & 63, wid = tid >> 6;
    int i = blockIdx.x * 1024 + tid;
    int v = (i < N_NODES) ? offs[i] : 0;
    int s = v;
#pragma unroll
    for (int d = 1; d < 64; d <<= 1) {
        int t = __shfl_up(s, (unsigned)d, 64);
        if (lane >= d) s += t;
    }
    if (lane == 63) wsum[wid] = s;
    __syncthreads();
    if (wid == 0) {
        int w = (lane < 16) ? wsum[lane] : 0;
#pragma unroll
        for (int d = 1; d < 16; d <<= 1) {
            int t = __shfl_up(w, (unsigned)d, 64);
            if (lane >= d) w += t;
        }
        if (lane < 16) wsum[lane] = w;
    }
    __syncthreads();
    int woff = (wid == 0) ? 0 : wsum[wid - 1];
    if (i < N_NODES) offs[i] = woff + s - v;     // exclusive within block
    if (tid == 0) bsum[blockIdx.x] = wsum[15];
}

// pass 2: exclusive scan of the <=128 block totals, in place. One block.
__global__ __launch_bounds__(128) void scan2_kernel(int* __restrict__ bsum, int nb)
{
    __shared__ int wsum2[2];
    int tid = threadIdx.x, lane = tid & 63, wid = tid >> 6;
    int v = (tid < nb) ? bsum[tid] : 0;
    int s = v;
#pragma unroll
    for (int d = 1; d < 64; d <<= 1) {
        int t = __shfl_up(s, (unsigned)d, 64);
        if (lane >= d) s += t;
    }
    if (lane == 63) wsum2[wid] = s;
    __syncthreads();
    int add = (wid == 1) ? wsum2[0] : 0;
    if (tid < nb) bsum[tid] = add + s - v;       // exclusive
}

// pass 3: add block offset; publish with atomicExch so fill's atomicAdd
// cursor RMW (other XCD) never sees a stale value.
__global__ __launch_bounds__(256) void scan3_kernel(
    int* __restrict__ offs, const int* __restrict__ bsum)
{
    int i = blockIdx.x * 256 + threadIdx.x;
    if (i < N_NODES) atomicExch(&offs[i], offs[i] + bsum[i >> 10]);
}

// eid2[slot] = (e, src[e]); offs becomes END offsets after this
// (start[n] = offs[n-1] afterwards, start[0] = 0).
__global__ __launch_bounds__(256) void fill_kernel(
    const int* __restrict__ src, const int* __restrict__ dst,
    int* __restrict__ offs, int2* __restrict__ eid2)
{
    int e = blockIdx.x * 256 + threadIdx.x;
    if (e < N_EDGES) {
        int d = dst[e];
        int pos = atomicAdd(&offs[d], 1);
        eid2[pos] = make_int2(e, src[e]);
    }
}

// Canonicalize each node's slot range to ascending edge-id order so the
// aggregation sum order is launch-invariant. Wave per node, 64-lane bitonic
// sort, INT_MAX padding. Degrees ~Poisson(10); P(deg>64) ~ 1e-40.
__global__ __launch_bounds__(256) void sort_kernel(
    const int* __restrict__ offs, int2* __restrict__ eid2)
{
    int gt = blockIdx.x * 256 + threadIdx.x;
    int n = gt >> 6;
    int lane = threadIdx.x & 63;
    if (n >= N_NODES) return;                 // wave-uniform
    int start = (n == 0) ? 0 : offs[n - 1];
    int end = offs[n];
    int deg = end - start;
    if (deg <= 1 || deg > 64) return;         // wave-uniform
    int ke = 0x7fffffff, vs = 0;
    if (lane < deg) { int2 t = eid2[start + lane]; ke = t.x; vs = t.y; }
#pragma unroll
    for (int k = 2; k <= 64; k <<= 1) {
        for (int j = k >> 1; j > 0; j >>= 1) {
            int partner = lane ^ j;
            int ke2 = __shfl(ke, partner, 64);
            int vs2 = __shfl(vs, partner, 64);
            bool up = ((lane & k) == 0);
            bool takemin = ((lane < partner) == up);
            bool sw = takemin ? (ke2 < ke) : (ke2 > ke);
            if (sw) { ke = ke2; vs = vs2; }
        }
    }
    if (lane < deg) eid2[start + lane] = make_int2(ke, vs);
}

// Wave-per-node aggregation, 4 edges per iteration, eid2 prefetched one
// iteration ahead so its latency overlaps the ea/x loads.
// lane = (edge-slot j = lane>>4) x (channel-quad q = lane&15).
__global__ __launch_bounds__(256) void agg_kernel(
    const float* __restrict__ x, const float* __restrict__ ea,
    const int2* __restrict__ eid2, const int* __restrict__ offs,
    float* __restrict__ agg)
{
    int gt = blockIdx.x * 256 + threadIdx.x;
    int n = gt >> 6;                         // wave-uniform
    int lane = threadIdx.x & 63;
    int j = lane >> 4, q = lane & 15;
    if (n >= N_NODES) return;
    int start = (n == 0) ? 0 : offs[n - 1];
    int end = offs[n];
    float4 acc = make_float4(0.f, 0.f, 0.f, 0.f);
    int idx = start + j;
    bool valid = idx < end;
    int2 p = valid ? eid2[idx] : make_int2(0, 0);
    for (int i = start; i < end; i += 4) {   // uniform trip count
        int2 cur = p;
        bool v = valid;
        int nidx = i + 4 + j;                // prefetch next iteration
        valid = nidx < end;
        if (valid) p = eid2[nidx];
        if (v) {
            float4 a = ((const float4*)(ea + (size_t)cur.x * HID))[q];
            float4 xv = ((const float4*)(x + (size_t)cur.y * HID))[q];
            acc.x += fmaxf(xv.x + a.x, 0.f);
            acc.y += fmaxf(xv.y + a.y, 0.f);
            acc.z += fmaxf(xv.z + a.z, 0.f);
            acc.w += fmaxf(xv.w + a.w, 0.f);
        }
    }
    // reduce over the 4 edge-slots: lanes {q, q+16, q+32, q+48}
    acc.x += __shfl_xor(acc.x, 32, 64);
    acc.y += __shfl_xor(acc.y, 32, 64);
    acc.z += __shfl_xor(acc.z, 32, 64);
    acc.w += __shfl_xor(acc.w, 32, 64);
    acc.x += __shfl_xor(acc.x, 16, 64);
    acc.y += __shfl_xor(acc.y, 16, 64);
    acc.z += __shfl_xor(acc.z, 16, 64);
    acc.w += __shfl_xor(acc.w, 16, 64);
    if (lane < 16)
        ((float4*)(agg + (size_t)n * HID))[q] = acc;
}

// Per-node MLP, outer-product form. Weights read with WAVE-UNIFORM addresses
// from global -> scalar (SMEM) loads, weight operands in SGPRs, zero LDS.
// __launch_bounds__(256,2): VGPR cap 256 so in[64]+o[64] stay in registers
// (round-4 default cap of ~84 spilled ~42MB to scratch: WRITE 68MB vs 26MB).
// o = (relu?)(W2 @ relu(W1 @ (agg+x) + b1) + b2) + x, in place on x.
__global__ __launch_bounds__(256, 2) void mlp_kernel(
    const float* __restrict__ agg,
    const float* __restrict__ W1, const float* __restrict__ b1,
    const float* __restrict__ W2T, const float* __restrict__ b2,
    float* __restrict__ x, int last_relu)
{
    int n = blockIdx.x * 256 + threadIdx.x;
    if (n >= N_NODES) return;

    const float4* ap = (const float4*)(agg + (size_t)n * HID);
    const float4* xp = (const float4*)(x + (size_t)n * HID);

    float in[HID];
#pragma unroll
    for (int c = 0; c < 16; ++c) {
        float4 a = ap[c], b = xp[c];
        in[4*c+0] = a.x + b.x;
        in[4*c+1] = a.y + b.y;
        in[4*c+2] = a.z + b.z;
        in[4*c+3] = a.w + b.w;
    }

    float o[HID];
#pragma unroll
    for (int c = 0; c < HID; ++c) o[c] = b2[c];   // uniform -> scalar loads

    for (int j = 0; j < HID; ++j) {
        const float4* w1p = (const float4*)(W1 + (j << 6));   // uniform addr
        float a0 = 0.f, a1 = 0.f, a2 = 0.f, a3 = 0.f;
#pragma unroll
        for (int c = 0; c < 16; c += 4) {
            float4 wa = w1p[c+0], wb = w1p[c+1], wc = w1p[c+2], wd = w1p[c+3];
            a0 += in[4*c+ 0]*wa.x + in[4*c+ 1]*wa.y + in[4*c+ 2]*wa.z + in[4*c+ 3]*wa.w;
            a1 += in[4*c+ 4]*wb.x + in[4*c+ 5]*wb.y + in[4*c+ 6]*wb.z + in[4*c+ 7]*wb.w;
            a2 += in[4*c+ 8]*wc.x + in[4*c+ 9]*wc.y + in[4*c+10]*wc.z + in[4*c+11]*wc.w;
            a3 += in[4*c+12]*wd.x + in[4*c+13]*wd.y + in[4*c+14]*wd.z + in[4*c+15]*wd.w;
        }
        float h = fmaxf((a0 + a1) + (a2 + a3) + b1[j], 0.f);
        const float4* w2p = (const float4*)(W2T + (j << 6));  // uniform addr
#pragma unroll
        for (int c = 0; c < 16; ++c) {
            float4 w = w2p[c];
            o[4*c+0] += h * w.x;
            o[4*c+1] += h * w.y;
            o[4*c+2] += h * w.z;
            o[4*c+3] += h * w.w;
        }
    }

    float* orow = x + (size_t)n * HID;   // in-place: row-private
#pragma unroll
    for (int c = 0; c < 16; ++c) {
        float4 xv = xp[c];
        float4 r;
        r.x = (last_relu ? fmaxf(o[4*c+0], 0.f) : o[4*c+0]) + xv.x;
        r.y = (last_relu ? fmaxf(o[4*c+1], 0.f) : o[4*c+1]) + xv.y;
        r.z = (last_relu ? fmaxf(o[4*c+2], 0.f) : o[4*c+2]) + xv.z;
        r.w = (last_relu ? fmaxf(o[4*c+3], 0.f) : o[4*c+3]) + xv.w;
        ((float4*)orow)[c] = r;
    }
}

extern "C" void kernel_launch(void* const* d_in, const int* in_sizes, int n_in,
                              void* d_out, int out_size, void* d_ws, size_t ws_size,
                              hipStream_t stream) {
    const float* node_emb = (const float*)d_in[0];
    const float* W1 = (const float*)d_in[1];
    const float* b1 = (const float*)d_in[2];
    const float* W2 = (const float*)d_in[3];
    const float* b2 = (const float*)d_in[4];
    const float* ea = (const float*)d_in[5];
    const int* z = (const int*)d_in[6];
    const int* ei = (const int*)d_in[7];
    const int* src = ei;            // edge_index[0] = message sender
    const int* dst = ei + N_EDGES;  // edge_index[1] = aggregation target

    float* x = (float*)d_out;                       // node features live here

    char* w = (char*)d_ws;
    float* agg = (float*)w;                    w += (size_t)N_NODES * HID * 4;  // 25.6 MB
    int2* eid2 = (int2*)w;                     w += (size_t)N_EDGES * 8;        // 8 MB
    int* offs = (int*)w;                       w += (size_t)N_NODES * 4;        // 0.4 MB
    int* bsum = (int*)w;                       w += 128 * 4;
    float* w2t = (float*)w;                    w += 3 * HID * HID * 4;          // 48 KB

    const int eb = (N_EDGES + 255) / 256;            // 3907
    const int gather_blocks = (N_NODES * 16) / 256;  // 6250
    const int nodewave_blocks = (N_NODES * 64) / 256; // 25000
    const int mlp_blocks = (N_NODES + 255) / 256;    // 391
    const int nscan = (N_NODES + 1023) / 1024;       // 98

    // ---- CSR build + weight transpose (once, reused by all 3 convs) ----
    hipMemsetAsync(offs, 0, N_NODES * sizeof(int), stream);
    gather_kernel<<<gather_blocks, 256, 0, stream>>>(node_emb, z, x);
    trans_kernel<<<48, 256, 0, stream>>>(W2, w2t);
    hist_kernel<<<eb, 256, 0, stream>>>(dst, offs);
    scan1_kernel<<<nscan, 1024, 0, stream>>>(offs, bsum);
    scan2_kernel<<<1, 128, 0, stream>>>(bsum, nscan);
    scan3_kernel<<<mlp_blocks, 256, 0, stream>>>(offs, bsum);
    fill_kernel<<<eb, 256, 0, stream>>>(src, dst, offs, eid2);
    sort_kernel<<<nodewave_blocks, 256, 0, stream>>>(offs, eid2);

    // ---- 3 convs, x updated in place in d_out ----
    for (int conv = 0; conv < 3; ++conv) {
        agg_kernel<<<nodewave_blocks, 256, 0, stream>>>(x, ea, eid2, offs, agg);
        mlp_kernel<<<mlp_blocks, 256, 0, stream>>>(
            agg, W1 + conv * HID * HID, b1 + conv * HID,
            w2t + conv * HID * HID, b2 + conv * HID,
            x, conv < 2 ? 1 : 0);
    }
}